// Round 5
// baseline (598.083 us; speedup 1.0000x reference)
//
#include <hip/hip_runtime.h>
#include <hip/hip_bf16.h>

// ---------------------------------------------------------------------------
// TENSSD layer, round 4: gemm256 K-loop split into 4 fine phases (T3):
// per phase {ds_read subtile, lgkmcnt(0), setprio, 16 MFMA, s_barrier} so
// concurrent waves occupy different pipes (LDS vs MFMA). Staging burst at
// tile top + counted vmcnt(8) (unchanged r3 ledger). B-frags held resident
// (24 ds_reads/K-tile instead of 32).
// Shapes fixed: B=4, T=4096, D=1024, K2=128, mlp=4096, M=16384.
// SSD collapses to a 21-tap complex FIR (mag<=0.183 -> exact in fp32).
// ---------------------------------------------------------------------------

#define FIR_LAG 20

typedef __attribute__((ext_vector_type(8))) short    bf16x8;
typedef __attribute__((ext_vector_type(4))) float    f32x4;
typedef __attribute__((ext_vector_type(4))) unsigned short ushort4_t;

__device__ __forceinline__ unsigned short f2bf(float f) {
    union { __hip_bfloat16 b; unsigned short u; } cv;
    cv.b = __float2bfloat16(f);
    return cv.u;
}
__device__ __forceinline__ float bf2f(unsigned short u) {
    return __uint_as_float((unsigned)u << 16);
}

__device__ __forceinline__ void gload_lds16(const unsigned short* g, unsigned short* l) {
    __builtin_amdgcn_global_load_lds(
        (const __attribute__((address_space(1))) unsigned int*)g,
        (__attribute__((address_space(3))) unsigned int*)l, 16, 0, 0);
}

// ---------------- fp32 -> bf16 conversion (8 elems/thread) -----------------
__global__ __launch_bounds__(256) void cvt_bf16_kernel(
    const float* __restrict__ in, unsigned short* __restrict__ out, int n)
{
    int i = (blockIdx.x * 256 + threadIdx.x) * 8;
    if (i >= n) return;
    float4 a = *(const float4*)(in + i);
    float4 b = *(const float4*)(in + i + 4);
    ushort4_t o0 = { f2bf(a.x), f2bf(a.y), f2bf(a.z), f2bf(a.w) };
    ushort4_t o1 = { f2bf(b.x), f2bf(b.y), f2bf(b.z), f2bf(b.w) };
    *(ushort4_t*)(out + i)     = o0;
    *(ushort4_t*)(out + i + 4) = o1;
}

// ---------------- LayerNorm -> bf16 (one block per row of 1024) ------------
__global__ __launch_bounds__(256) void ln_kernel(
    const float* __restrict__ in, const float* __restrict__ g,
    const float* __restrict__ b, unsigned short* __restrict__ out)
{
    const size_t row = blockIdx.x;
    const int t = threadIdx.x;
    float4 v = ((const float4*)(in + row * 1024))[t];
    float s  = v.x + v.y + v.z + v.w;
    float s2 = v.x*v.x + v.y*v.y + v.z*v.z + v.w*v.w;
    #pragma unroll
    for (int o = 32; o > 0; o >>= 1) {
        s  += __shfl_down(s, o);
        s2 += __shfl_down(s2, o);
    }
    __shared__ float red[8];
    __shared__ float mv[2];
    const int wv = t >> 6;
    if ((t & 63) == 0) { red[wv] = s; red[4 + wv] = s2; }
    __syncthreads();
    if (t == 0) {
        float a  = red[0] + red[1] + red[2] + red[3];
        float a2 = red[4] + red[5] + red[6] + red[7];
        float mean = a * (1.f / 1024.f);
        float var  = a2 * (1.f / 1024.f) - mean * mean;
        mv[0] = mean;
        mv[1] = rsqrtf(var + 1e-5f);
    }
    __syncthreads();
    const float mean = mv[0], rstd = mv[1];
    float4 gg = ((const float4*)g)[t];
    float4 bb = ((const float4*)b)[t];
    ushort4_t o4 = { f2bf((v.x - mean) * rstd * gg.x + bb.x),
                     f2bf((v.y - mean) * rstd * gg.y + bb.y),
                     f2bf((v.z - mean) * rstd * gg.z + bb.z),
                     f2bf((v.w - mean) * rstd * gg.w + bb.w) };
    *(ushort4_t*)(out + row * 1024 + t * 4) = o4;
}

// ---------------- Depthwise causal conv(4) + SiLU --------------------------
__global__ __launch_bounds__(256) void conv_silu_kernel(
    const float* __restrict__ bp, const float* __restrict__ cw,
    const float* __restrict__ cb, float* __restrict__ beta, int T)
{
    const int idx = blockIdx.x * 256 + threadIdx.x;   // over M*128
    const int c  = idx & 127;
    const int bt = idx >> 7;
    const int t  = bt & (T - 1);
    float acc = cb[c];
    #pragma unroll
    for (int j = 0; j < 4; ++j) {
        int ts = t - 3 + j;
        if (ts >= 0) acc += cw[c * 4 + j] * bp[(size_t)(bt - 3 + j) * 128 + c];
    }
    beta[(size_t)bt * 128 + c] = acc / (1.f + expf(-acc));
}

// ---------------- Truncated complex FIR + coupling -> eig (f32 + bf16) -----
__global__ __launch_bounds__(256) void fir_coupling_kernel(
    const float* __restrict__ beta, const float* __restrict__ log_decay,
    const float* __restrict__ freq, const float* __restrict__ coup,
    float* __restrict__ eig, unsigned short* __restrict__ eig_bf, int T)
{
    __shared__ float sb[65][128];
    const int blk = blockIdx.x;
    const int nch = T >> 6;
    const int b = blk / nch;
    const int n = blk - b * nch;
    const size_t base = ((size_t)b * T + (size_t)n * 64) * 128;
    const int tid = threadIdx.x;

    #pragma unroll
    for (int it = 0; it < 8; ++it) {
        int f = tid + it * 256;
        int r = f >> 5, c4 = f & 31;
        *(float4*)&sb[1 + r][c4 * 4] =
            *(const float4*)(beta + base + (size_t)r * 128 + c4 * 4);
    }
    if (tid < 32) {
        float4 z = make_float4(0.f, 0.f, 0.f, 0.f);
        *(float4*)&sb[0][tid * 4] =
            (n > 0) ? *(const float4*)(beta + base - 128 + tid * 4) : z;
    }
    __syncthreads();

    const int k  = tid & 63;
    const int tq = tid >> 6;
    const float mag = 1.f / (1.f + expf(-log_decay[k]));
    const float w = freq[k];
    const float rr = mag * cosf(w), ri = mag * sinf(w);
    float cr[16], ci[16];
    #pragma unroll
    for (int m = 0; m < 16; ++m) { cr[m] = 0.f; ci[m] = 0.f; }
    float zr = 1.f, zi = 0.f;
    for (int e = 0; e <= FIR_LAG; ++e) {
        #pragma unroll
        for (int m = 0; m < 16; ++m) {
            int i = tq * 16 + m;
            int src = i + e;
            if (src <= 63) {
                float br = sb[1 + src][k];
                float bi = sb[1 + src][64 + k];
                cr[m] += zr * br - zi * bi;
                ci[m] += zr * bi + zi * br;
            }
        }
        float nzr = zr * rr - zi * ri;
        zi = zr * ri + zi * rr;
        zr = nzr;
    }
    if (tq == 0) {
        cr[0] += sb[0][k];
        ci[0] += sb[0][64 + k];
    }
    __syncthreads();
    #pragma unroll
    for (int m = 0; m < 16; ++m) {
        int i = tq * 16 + m;
        sb[i][k] = cr[m];
        sb[i][64 + k] = ci[m];
    }
    __syncthreads();
    const int h = k >> 4, j = k & 15;
    float cp[16];
    #pragma unroll
    for (int q = 0; q < 16; ++q) cp[q] = coup[(h * 16 + j) * 16 + q];
    #pragma unroll
    for (int m = 0; m < 16; ++m) {
        int i = tq * 16 + m;
        float sr = 0.f, si = 0.f;
        #pragma unroll
        for (int q = 0; q < 16; ++q) {
            sr += cp[q] * sb[i][h * 16 + q];
            si += cp[q] * sb[i][64 + h * 16 + q];
        }
        size_t o = base + (size_t)i * 128;
        eig[o + k]         = sr;
        eig[o + 64 + k]    = si;
        eig_bf[o + k]      = f2bf(sr);
        eig_bf[o + 64 + k] = f2bf(si);
    }
}

// ---------------- 128^2 MFMA GEMM (kept for in_proj, N=128) ----------------
__global__ __launch_bounds__(256) void gemm_mfma_f32out(
    const unsigned short* __restrict__ A, const unsigned short* __restrict__ B,
    float* __restrict__ C, int M, int N, int K)
{
    constexpr int BM = 128, BK = 32;
    __shared__ unsigned short As[BM * BK];
    __shared__ unsigned short Bs[BM * BK];
    const int tid  = threadIdx.x;
    const int lane = tid & 63;
    const int wave = tid >> 6;
    const int wm = wave >> 1, wn = wave & 1;
    const int bm = blockIdx.y * BM;
    const int bn = blockIdx.x * BM;

    f32x4 acc[4][4];
    #pragma unroll
    for (int m = 0; m < 4; ++m)
        #pragma unroll
        for (int n = 0; n < 4; ++n) acc[m][n] = (f32x4){0.f, 0.f, 0.f, 0.f};

    const int frow = lane & 15;
    const int fk   = (lane >> 4) * 8;
    const int srow = tid >> 2;
    const int sc   = (tid & 3) * 8;

    for (int k0 = 0; k0 < K; k0 += BK) {
        #pragma unroll
        for (int it = 0; it < 2; ++it) {
            int row = it * 64 + srow;
            int ci  = it * 256 + tid;
            gload_lds16(A + (size_t)(bm + row) * K + k0 + sc, As + ci * 8);
            gload_lds16(B + (size_t)(bn + row) * K + k0 + sc, Bs + ci * 8);
        }
        __syncthreads();
        bf16x8 af[4], bfr[4];
        #pragma unroll
        for (int m = 0; m < 4; ++m)
            af[m] = *(const bf16x8*)(As + (wm * 64 + m * 16 + frow) * BK + fk);
        #pragma unroll
        for (int n = 0; n < 4; ++n)
            bfr[n] = *(const bf16x8*)(Bs + (wn * 64 + n * 16 + frow) * BK + fk);
        #pragma unroll
        for (int m = 0; m < 4; ++m)
            #pragma unroll
            for (int n = 0; n < 4; ++n)
                acc[m][n] = __builtin_amdgcn_mfma_f32_16x16x32_bf16(
                    af[m], bfr[n], acc[m][n], 0, 0, 0);
        __syncthreads();
    }

    const int r0 = (lane >> 4) * 4;
    const int cc = lane & 15;
    #pragma unroll
    for (int m = 0; m < 4; ++m)
        #pragma unroll
        for (int n = 0; n < 4; ++n) {
            const int col = bn + wn * 64 + n * 16 + cc;
            #pragma unroll
            for (int j = 0; j < 4; ++j) {
                const int row = bm + wm * 64 + m * 16 + r0 + j;
                C[(size_t)row * N + col] = acc[m][n][j];
            }
        }
}

// ---------------- 256^2-tile 8-wave MFMA GEMM: C = epi(A @ B^T) ------------
// A: (M,K) bf16, B: (N,K) bf16, row-major. BK=64, double-buffered LDS,
// T1 XCD swizzle, T2 both-sides XOR swizzle, T3 4-phase interleave,
// T4 counted vmcnt, T5 setprio.
// EPI 0: C fp32 = acc
// EPI 1: C fp32 = p1 + sigmoid(acc + bias[col]) * bf2f(p2)  (gate, p2 bf16)
// EPI 2: C bf16 = silu(acc + bias[col])                     (mlp1)
// EPI 3: C fp32 = p1 + acc + bias[col]                      (mlp2)
// EPI 4: C bf16 = acc                                       (out_proj -> h)
template<int EPI, typename OT>
__global__ __launch_bounds__(512) void gemm256(
    const unsigned short* __restrict__ A, const unsigned short* __restrict__ B,
    OT* __restrict__ C, int M, int N, int K,
    const float* __restrict__ bias,
    const float* __restrict__ p1, const unsigned short* __restrict__ p2)
{
    constexpr int BM = 256, BN = 256, BK = 64;
    __shared__ unsigned short As[2][BM * BK];   // 32 KB per buffer
    __shared__ unsigned short Bs[2][BN * BK];
    const int tid  = threadIdx.x;
    const int lane = tid & 63;
    const int wave = tid >> 6;
    const int wm = wave >> 2;        // 0..1
    const int wn = wave & 3;         // 0..3

    // T1: bijective XCD-aware swizzle (m204): contiguous chunk per XCD.
    const int nbn = N / BN;
    const int nwg = gridDim.x;
    int orig = blockIdx.x;
    int xcd = orig & 7, ixc = orig >> 3;
    int q = nwg >> 3, r = nwg & 7;
    int wgid = (xcd < r ? xcd * (q + 1) : r * (q + 1) + (xcd - r) * q) + ixc;
    const int bm = (wgid / nbn) * BM;
    const int bn = (wgid % nbn) * BN;

    f32x4 acc[8][4];
    #pragma unroll
    for (int m = 0; m < 8; ++m)
        #pragma unroll
        for (int n = 0; n < 4; ++n) acc[m][n] = (f32x4){0.f, 0.f, 0.f, 0.f};

    const int srow8  = tid >> 3;          // 0..63
    const int schunk = tid & 7;           // 16B chunk within 128B row

    const int frow = lane & 15;
    const int l47  = lane & 7;
    const int lk   = lane >> 4;           // 0..3

    const unsigned short* Abase = A + (size_t)bm * K;
    const unsigned short* Bbase = B + (size_t)bn * K;

// 4 gload_lds per call -> 8 VMEM per (A,B) pair per wave
#define STAGE(G, DS, k0)                                                     \
    {                                                                        \
        _Pragma("unroll")                                                    \
        for (int s = 0; s < 4; ++s) {                                        \
            int row = s * 64 + srow8;                                        \
            int gch = schunk ^ (row & 7);                                    \
            gload_lds16((G) + (size_t)row * K + (k0) + gch * 8,              \
                        (DS) + s * 4096 + tid * 8);                          \
        }                                                                    \
    }

// load A-fragments for half MH (8 x ds_read_b128)
#define LDA(MH)                                                              \
    _Pragma("unroll")                                                        \
    for (int m = 0; m < 4; ++m)                                              \
        _Pragma("unroll")                                                    \
        for (int kk = 0; kk < 2; ++kk)                                       \
            af[m][kk] = *(const bf16x8*)(a_ +                                \
                (wm * 128 + ((MH) * 4 + m) * 16 + frow) * 64 +               \
                ((kk * 4 + lk) ^ l47) * 8);

// load B-fragments for half NH into FR (4 x ds_read_b128)
#define LDB(FR, NH)                                                          \
    _Pragma("unroll")                                                        \
    for (int n = 0; n < 2; ++n)                                              \
        _Pragma("unroll")                                                    \
        for (int kk = 0; kk < 2; ++kk)                                       \
            FR[n][kk] = *(const bf16x8*)(b_ +                                \
                (wn * 64 + ((NH) * 2 + n) * 16 + frow) * 64 +                \
                ((kk * 4 + lk) ^ l47) * 8);

// one phase's MFMA cluster: quadrant (MH, NH) with B-frags FR, 16 MFMA
#define PH_MFMA(MH, NH, FR)                                                  \
    asm volatile("s_waitcnt lgkmcnt(0)" ::: "memory");                       \
    __builtin_amdgcn_sched_barrier(0);                                       \
    __builtin_amdgcn_s_setprio(1);                                           \
    _Pragma("unroll")                                                        \
    for (int m = 0; m < 4; ++m)                                              \
        _Pragma("unroll")                                                    \
        for (int n = 0; n < 2; ++n)                                          \
            _Pragma("unroll")                                                \
            for (int kk = 0; kk < 2; ++kk)                                   \
                acc[(MH) * 4 + m][(NH) * 2 + n] =                            \
                    __builtin_amdgcn_mfma_f32_16x16x32_bf16(                 \
                        af[m][kk], FR[n][kk],                                \
                        acc[(MH) * 4 + m][(NH) * 2 + n], 0, 0, 0);           \
    __builtin_amdgcn_s_setprio(0);                                           \
    __builtin_amdgcn_s_barrier();                                            \
    __builtin_amdgcn_sched_barrier(0);

    // prologue: stage K-tile 0
    STAGE(Abase, As[0], 0)
    STAGE(Bbase, Bs[0], 0)

    const int KT = K / BK;
    for (int t = 0; t < KT; ++t) {
        const unsigned short* a_ = As[t & 1];
        const unsigned short* b_ = Bs[t & 1];
        // burst-issue next tile's staging; counted wait leaves it in flight
        if (t + 1 < KT) {
            STAGE(Abase, As[(t + 1) & 1], (t + 1) * BK)
            STAGE(Bbase, Bs[(t + 1) & 1], (t + 1) * BK)
            asm volatile("s_waitcnt vmcnt(8)" ::: "memory");   // stage(t) done
        } else {
            asm volatile("s_waitcnt vmcnt(0)" ::: "memory");
        }
        __builtin_amdgcn_s_barrier();          // buf[t&1] visible to all
        __builtin_amdgcn_sched_barrier(0);

        bf16x8 af[4][2], bfr0[2][2], bfr1[2][2];
        // P1: A-half0 + B-half0 reads, MFMA quadrant (0,0)
        LDA(0)
        LDB(bfr0, 0)
        PH_MFMA(0, 0, bfr0)
        // P2: B-half1 reads, MFMA (0,1)
        LDB(bfr1, 1)
        PH_MFMA(0, 1, bfr1)
        // P3: A-half1 reads, MFMA (1,1) with resident bfr1
        LDA(1)
        PH_MFMA(1, 1, bfr1)
        // P4: no ds_reads, MFMA (1,0) with resident bfr0
        PH_MFMA(1, 0, bfr0)
        // P4's trailing barrier releases buf[t&1] (last read was in P3)
    }
#undef STAGE
#undef LDA
#undef LDB
#undef PH_MFMA

    const int r0 = (lane >> 4) * 4;
    const int cc = lane & 15;
    #pragma unroll
    for (int m = 0; m < 8; ++m) {
        #pragma unroll
        for (int n = 0; n < 4; ++n) {
            const int col = bn + wn * 64 + n * 16 + cc;
            #pragma unroll
            for (int j = 0; j < 4; ++j) {
                const int row = bm + wm * 128 + m * 16 + r0 + j;
                const size_t idx = (size_t)row * N + col;
                const float v = acc[m][n][j];
                if constexpr (EPI == 0) {
                    C[idx] = v;
                } else if constexpr (EPI == 1) {
                    float pre = v + bias[col];
                    float gt = 1.f / (1.f + expf(-pre));
                    C[idx] = p1[idx] + gt * bf2f(p2[idx]);
                } else if constexpr (EPI == 2) {
                    float pre = v + bias[col];
                    C[idx] = (OT)__float2bfloat16(pre / (1.f + expf(-pre)));
                } else if constexpr (EPI == 3) {
                    C[idx] = p1[idx] + v + bias[col];
                } else {
                    C[idx] = (OT)__float2bfloat16(v);
                }
            }
        }
    }
}

// ---------------------------------------------------------------------------
extern "C" void kernel_launch(void* const* d_in, const int* in_sizes, int n_in,
                              void* d_out, int out_size, void* d_ws, size_t ws_size,
                              hipStream_t stream)
{
    const float* x        = (const float*)d_in[0];
    const float* in_proj  = (const float*)d_in[1];
    const float* conv_w   = (const float*)d_in[2];
    const float* conv_b   = (const float*)d_in[3];
    const float* log_dec  = (const float*)d_in[4];
    const float* freq     = (const float*)d_in[5];
    const float* coup     = (const float*)d_in[6];
    const float* out_proj = (const float*)d_in[7];
    const float* gate_w   = (const float*)d_in[8];
    const float* gate_b   = (const float*)d_in[9];
    const float* mlp_w1   = (const float*)d_in[10];
    const float* mlp_b1   = (const float*)d_in[11];
    const float* mlp_w2   = (const float*)d_in[12];
    const float* mlp_b2   = (const float*)d_in[13];
    const float* ln1_g    = (const float*)d_in[14];
    const float* ln1_b    = (const float*)d_in[15];
    const float* ln2_g    = (const float*)d_in[16];
    const float* ln2_b    = (const float*)d_in[17];

    const int B = 4, T = 4096, D = 1024;
    const int M = B * T;                        // 16384

    float* out = (float*)d_out;                 // (M, D) final output 0
    float* eig = out + (size_t)M * D;           // (M, 128) final output 1
    float* bpre = eig;                          // temp: beta_pre in eig region

    char* w = (char*)d_ws;
    unsigned short* xn_bf = (unsigned short*)w; w += (size_t)M * 1024 * 2;
    float* x1             = (float*)w;          w += (size_t)M * 1024 * 4;
    float* beta           = (float*)w;          w += (size_t)M * 128 * 4;
    unsigned short* mid   = (unsigned short*)w; w += (size_t)M * 4096 * 2;
    unsigned short* eig_bf= (unsigned short*)w; w += (size_t)M * 128 * 2;
    unsigned short* wb_inproj = (unsigned short*)w; w += (size_t)128 * 1024 * 2;
    unsigned short* wb_outproj= (unsigned short*)w; w += (size_t)1024 * 128 * 2;
    unsigned short* wb_gate   = (unsigned short*)w; w += (size_t)1024 * 1024 * 2;
    unsigned short* wb_mlp1   = (unsigned short*)w; w += (size_t)4096 * 1024 * 2;
    unsigned short* wb_mlp2   = (unsigned short*)w; w += (size_t)1024 * 4096 * 2;
    // h (bf16) lives in the first 32 MB of mid: dead once mlp1 writes mid.
    unsigned short* h_bf = mid;

    // 0. weight conversions fp32 -> bf16
    cvt_bf16_kernel<<<(128 * 1024) / 2048, 256, 0, stream>>>(in_proj, wb_inproj, 128 * 1024);
    cvt_bf16_kernel<<<(1024 * 128) / 2048, 256, 0, stream>>>(out_proj, wb_outproj, 1024 * 128);
    cvt_bf16_kernel<<<(1024 * 1024) / 2048, 256, 0, stream>>>(gate_w, wb_gate, 1024 * 1024);
    cvt_bf16_kernel<<<(4096 * 1024) / 2048, 256, 0, stream>>>(mlp_w1, wb_mlp1, 4096 * 1024);
    cvt_bf16_kernel<<<(1024 * 4096) / 2048, 256, 0, stream>>>(mlp_w2, wb_mlp2, 1024 * 4096);

    // 1. LN1 -> bf16
    ln_kernel<<<M, 256, 0, stream>>>(x, ln1_g, ln1_b, xn_bf);
    // 2. in_proj: beta_pre = xn @ in_proj_w.T   (M,128) fp32
    gemm_mfma_f32out<<<dim3(1, M / 128), 256, 0, stream>>>(
        xn_bf, wb_inproj, bpre, M, 128, 1024);
    // 3. depthwise conv + silu
    conv_silu_kernel<<<(M * 128) / 256, 256, 0, stream>>>(bpre, conv_w, conv_b, beta, T);
    // 4. FIR + coupling -> eig (output 1, fp32) + eig_bf
    fir_coupling_kernel<<<B * (T / 64), 256, 0, stream>>>(
        beta, log_dec, freq, coup, eig, eig_bf, T);
    // 5. out_proj: h = eig @ out_proj_w.T   (M, D) bf16, staged in mid region
    gemm256<4, __hip_bfloat16><<<(M / 256) * (1024 / 256), 512, 0, stream>>>(
        eig_bf, wb_outproj, (__hip_bfloat16*)h_bf, M, 1024, 128,
        nullptr, nullptr, nullptr);
    // 6. gate fused: x1 = x + sigmoid(xn @ gate_w.T + gate_b) * h
    gemm256<1, float><<<(M / 256) * (1024 / 256), 512, 0, stream>>>(
        xn_bf, wb_gate, x1, M, 1024, 1024, gate_b, x, h_bf);
    // 7. LN2 -> bf16 (reuse xn_bf)
    ln_kernel<<<M, 256, 0, stream>>>(x1, ln2_g, ln2_b, xn_bf);
    // 8. mlp1: mid = bf16(silu(xn2 @ mlp_w1.T + b1))   (M, 4096)
    gemm256<2, __hip_bfloat16><<<(M / 256) * (4096 / 256), 512, 0, stream>>>(
        xn_bf, wb_mlp1, (__hip_bfloat16*)mid, M, 4096, 1024, mlp_b1, nullptr, nullptr);
    // 9. mlp2: out = x1 + mid @ mlp_w2.T + b2   (final output 0)
    gemm256<3, float><<<(M / 256) * (1024 / 256), 512, 0, stream>>>(
        mid, wb_mlp2, out, M, 1024, 4096, mlp_b2, x1, nullptr);
}

// Round 6
// 563.455 us; speedup vs baseline: 1.0615x; 1.0615x over previous
//
#include <hip/hip_runtime.h>
#include <hip/hip_bf16.h>

// ---------------------------------------------------------------------------
// TENSSD layer, round 5: faithful m201-style 8-phase gemm256.
// K-half (32) granularity: 4 rotating LDS regions per matrix ([256][32] bf16,
// chunk^=(row&3) both-sides swizzle). Per phase: {ds_read frags + 2
// global_load_lds (khalf kh+3) -> s_barrier -> lgkmcnt(0) -> setprio ->
// 16 MFMA -> s_barrier}. vmcnt(8/4/0) ledger once per khalf, never drained
// mid-loop (3 khalves in flight). T1 XCD swizzle kept.
// Shapes fixed: B=4, T=4096, D=1024, K2=128, mlp=4096, M=16384.
// SSD collapses to a 21-tap complex FIR (mag<=0.183 -> exact in fp32).
// ---------------------------------------------------------------------------

#define FIR_LAG 20

typedef __attribute__((ext_vector_type(8))) short    bf16x8;
typedef __attribute__((ext_vector_type(4))) float    f32x4;
typedef __attribute__((ext_vector_type(4))) unsigned short ushort4_t;

__device__ __forceinline__ unsigned short f2bf(float f) {
    union { __hip_bfloat16 b; unsigned short u; } cv;
    cv.b = __float2bfloat16(f);
    return cv.u;
}
__device__ __forceinline__ float bf2f(unsigned short u) {
    return __uint_as_float((unsigned)u << 16);
}

__device__ __forceinline__ void gload_lds16(const unsigned short* g, unsigned short* l) {
    __builtin_amdgcn_global_load_lds(
        (const __attribute__((address_space(1))) unsigned int*)g,
        (__attribute__((address_space(3))) unsigned int*)l, 16, 0, 0);
}

// ---------------- fp32 -> bf16 conversion (8 elems/thread) -----------------
__global__ __launch_bounds__(256) void cvt_bf16_kernel(
    const float* __restrict__ in, unsigned short* __restrict__ out, int n)
{
    int i = (blockIdx.x * 256 + threadIdx.x) * 8;
    if (i >= n) return;
    float4 a = *(const float4*)(in + i);
    float4 b = *(const float4*)(in + i + 4);
    ushort4_t o0 = { f2bf(a.x), f2bf(a.y), f2bf(a.z), f2bf(a.w) };
    ushort4_t o1 = { f2bf(b.x), f2bf(b.y), f2bf(b.z), f2bf(b.w) };
    *(ushort4_t*)(out + i)     = o0;
    *(ushort4_t*)(out + i + 4) = o1;
}

// ---------------- LayerNorm -> bf16 (one block per row of 1024) ------------
__global__ __launch_bounds__(256) void ln_kernel(
    const float* __restrict__ in, const float* __restrict__ g,
    const float* __restrict__ b, unsigned short* __restrict__ out)
{
    const size_t row = blockIdx.x;
    const int t = threadIdx.x;
    float4 v = ((const float4*)(in + row * 1024))[t];
    float s  = v.x + v.y + v.z + v.w;
    float s2 = v.x*v.x + v.y*v.y + v.z*v.z + v.w*v.w;
    #pragma unroll
    for (int o = 32; o > 0; o >>= 1) {
        s  += __shfl_down(s, o);
        s2 += __shfl_down(s2, o);
    }
    __shared__ float red[8];
    __shared__ float mv[2];
    const int wv = t >> 6;
    if ((t & 63) == 0) { red[wv] = s; red[4 + wv] = s2; }
    __syncthreads();
    if (t == 0) {
        float a  = red[0] + red[1] + red[2] + red[3];
        float a2 = red[4] + red[5] + red[6] + red[7];
        float mean = a * (1.f / 1024.f);
        float var  = a2 * (1.f / 1024.f) - mean * mean;
        mv[0] = mean;
        mv[1] = rsqrtf(var + 1e-5f);
    }
    __syncthreads();
    const float mean = mv[0], rstd = mv[1];
    float4 gg = ((const float4*)g)[t];
    float4 bb = ((const float4*)b)[t];
    ushort4_t o4 = { f2bf((v.x - mean) * rstd * gg.x + bb.x),
                     f2bf((v.y - mean) * rstd * gg.y + bb.y),
                     f2bf((v.z - mean) * rstd * gg.z + bb.z),
                     f2bf((v.w - mean) * rstd * gg.w + bb.w) };
    *(ushort4_t*)(out + row * 1024 + t * 4) = o4;
}

// ---------------- Depthwise causal conv(4) + SiLU --------------------------
__global__ __launch_bounds__(256) void conv_silu_kernel(
    const float* __restrict__ bp, const float* __restrict__ cw,
    const float* __restrict__ cb, float* __restrict__ beta, int T)
{
    const int idx = blockIdx.x * 256 + threadIdx.x;   // over M*128
    const int c  = idx & 127;
    const int bt = idx >> 7;
    const int t  = bt & (T - 1);
    float acc = cb[c];
    #pragma unroll
    for (int j = 0; j < 4; ++j) {
        int ts = t - 3 + j;
        if (ts >= 0) acc += cw[c * 4 + j] * bp[(size_t)(bt - 3 + j) * 128 + c];
    }
    beta[(size_t)bt * 128 + c] = acc / (1.f + expf(-acc));
}

// ---------------- Truncated complex FIR + coupling -> eig (f32 + bf16) -----
__global__ __launch_bounds__(256) void fir_coupling_kernel(
    const float* __restrict__ beta, const float* __restrict__ log_decay,
    const float* __restrict__ freq, const float* __restrict__ coup,
    float* __restrict__ eig, unsigned short* __restrict__ eig_bf, int T)
{
    __shared__ float sb[65][128];
    const int blk = blockIdx.x;
    const int nch = T >> 6;
    const int b = blk / nch;
    const int n = blk - b * nch;
    const size_t base = ((size_t)b * T + (size_t)n * 64) * 128;
    const int tid = threadIdx.x;

    #pragma unroll
    for (int it = 0; it < 8; ++it) {
        int f = tid + it * 256;
        int r = f >> 5, c4 = f & 31;
        *(float4*)&sb[1 + r][c4 * 4] =
            *(const float4*)(beta + base + (size_t)r * 128 + c4 * 4);
    }
    if (tid < 32) {
        float4 z = make_float4(0.f, 0.f, 0.f, 0.f);
        *(float4*)&sb[0][tid * 4] =
            (n > 0) ? *(const float4*)(beta + base - 128 + tid * 4) : z;
    }
    __syncthreads();

    const int k  = tid & 63;
    const int tq = tid >> 6;
    const float mag = 1.f / (1.f + expf(-log_decay[k]));
    const float w = freq[k];
    const float rr = mag * cosf(w), ri = mag * sinf(w);
    float cr[16], ci[16];
    #pragma unroll
    for (int m = 0; m < 16; ++m) { cr[m] = 0.f; ci[m] = 0.f; }
    float zr = 1.f, zi = 0.f;
    for (int e = 0; e <= FIR_LAG; ++e) {
        #pragma unroll
        for (int m = 0; m < 16; ++m) {
            int i = tq * 16 + m;
            int src = i + e;
            if (src <= 63) {
                float br = sb[1 + src][k];
                float bi = sb[1 + src][64 + k];
                cr[m] += zr * br - zi * bi;
                ci[m] += zr * bi + zi * br;
            }
        }
        float nzr = zr * rr - zi * ri;
        zi = zr * ri + zi * rr;
        zr = nzr;
    }
    if (tq == 0) {
        cr[0] += sb[0][k];
        ci[0] += sb[0][64 + k];
    }
    __syncthreads();
    #pragma unroll
    for (int m = 0; m < 16; ++m) {
        int i = tq * 16 + m;
        sb[i][k] = cr[m];
        sb[i][64 + k] = ci[m];
    }
    __syncthreads();
    const int h = k >> 4, j = k & 15;
    float cp[16];
    #pragma unroll
    for (int q = 0; q < 16; ++q) cp[q] = coup[(h * 16 + j) * 16 + q];
    #pragma unroll
    for (int m = 0; m < 16; ++m) {
        int i = tq * 16 + m;
        float sr = 0.f, si = 0.f;
        #pragma unroll
        for (int q = 0; q < 16; ++q) {
            sr += cp[q] * sb[i][h * 16 + q];
            si += cp[q] * sb[i][64 + h * 16 + q];
        }
        size_t o = base + (size_t)i * 128;
        eig[o + k]         = sr;
        eig[o + 64 + k]    = si;
        eig_bf[o + k]      = f2bf(sr);
        eig_bf[o + 64 + k] = f2bf(si);
    }
}

// ---------------- 128^2 MFMA GEMM (kept for in_proj, N=128) ----------------
__global__ __launch_bounds__(256) void gemm_mfma_f32out(
    const unsigned short* __restrict__ A, const unsigned short* __restrict__ B,
    float* __restrict__ C, int M, int N, int K)
{
    constexpr int BM = 128, BK = 32;
    __shared__ unsigned short As[BM * BK];
    __shared__ unsigned short Bs[BM * BK];
    const int tid  = threadIdx.x;
    const int lane = tid & 63;
    const int wave = tid >> 6;
    const int wm = wave >> 1, wn = wave & 1;
    const int bm = blockIdx.y * BM;
    const int bn = blockIdx.x * BM;

    f32x4 acc[4][4];
    #pragma unroll
    for (int m = 0; m < 4; ++m)
        #pragma unroll
        for (int n = 0; n < 4; ++n) acc[m][n] = (f32x4){0.f, 0.f, 0.f, 0.f};

    const int frow = lane & 15;
    const int fk   = (lane >> 4) * 8;
    const int srow = tid >> 2;
    const int sc   = (tid & 3) * 8;

    for (int k0 = 0; k0 < K; k0 += BK) {
        #pragma unroll
        for (int it = 0; it < 2; ++it) {
            int row = it * 64 + srow;
            int ci  = it * 256 + tid;
            gload_lds16(A + (size_t)(bm + row) * K + k0 + sc, As + ci * 8);
            gload_lds16(B + (size_t)(bn + row) * K + k0 + sc, Bs + ci * 8);
        }
        __syncthreads();
        bf16x8 af[4], bfr[4];
        #pragma unroll
        for (int m = 0; m < 4; ++m)
            af[m] = *(const bf16x8*)(As + (wm * 64 + m * 16 + frow) * BK + fk);
        #pragma unroll
        for (int n = 0; n < 4; ++n)
            bfr[n] = *(const bf16x8*)(Bs + (wn * 64 + n * 16 + frow) * BK + fk);
        #pragma unroll
        for (int m = 0; m < 4; ++m)
            #pragma unroll
            for (int n = 0; n < 4; ++n)
                acc[m][n] = __builtin_amdgcn_mfma_f32_16x16x32_bf16(
                    af[m], bfr[n], acc[m][n], 0, 0, 0);
        __syncthreads();
    }

    const int r0 = (lane >> 4) * 4;
    const int cc = lane & 15;
    #pragma unroll
    for (int m = 0; m < 4; ++m)
        #pragma unroll
        for (int n = 0; n < 4; ++n) {
            const int col = bn + wn * 64 + n * 16 + cc;
            #pragma unroll
            for (int j = 0; j < 4; ++j) {
                const int row = bm + wm * 64 + m * 16 + r0 + j;
                C[(size_t)row * N + col] = acc[m][n][j];
            }
        }
}

// ---------------- 256^2-tile 8-wave 8-phase MFMA GEMM ----------------------
// A: (M,K) bf16, B: (N,K) bf16, row-major. K-half (32) pipeline, 4 rotating
// LDS regions per matrix. EPI as before.
template<int EPI, typename OT>
__global__ __launch_bounds__(512) void gemm256(
    const unsigned short* __restrict__ A, const unsigned short* __restrict__ B,
    OT* __restrict__ C, int M, int N, int K,
    const float* __restrict__ bias,
    const float* __restrict__ p1, const unsigned short* __restrict__ p2)
{
    constexpr int BM = 256, BN = 256;
    __shared__ unsigned short Asw[4 * 256 * 32];   // 64 KB: 4 regions [256][32]
    __shared__ unsigned short Bsw[4 * 256 * 32];   // 64 KB
    const int tid  = threadIdx.x;
    const int lane = tid & 63;
    const int wave = tid >> 6;
    const int wm = wave >> 2;        // 0..1
    const int wn = wave & 3;         // 0..3

    // T1: bijective XCD-aware swizzle (m204): contiguous chunk per XCD.
    const int nbn = N / BN;
    const int nwg = gridDim.x;
    int orig = blockIdx.x;
    int xcd = orig & 7, ixc = orig >> 3;
    int q = nwg >> 3, r = nwg & 7;
    int wgid = (xcd < r ? xcd * (q + 1) : r * (q + 1) + (xcd - r) * q) + ixc;
    const int bm = (wgid / nbn) * BM;
    const int bn = (wgid % nbn) * BN;

    f32x4 acc[8][4];
    #pragma unroll
    for (int m = 0; m < 8; ++m)
        #pragma unroll
        for (int n = 0; n < 4; ++n) acc[m][n] = (f32x4){0.f, 0.f, 0.f, 0.f};

    const int frow   = lane & 15;
    const int lk     = lane >> 4;            // 0..3 (k-chunk of 8 bf16)
    const int achunk = lk ^ (frow & 3);      // swizzled read chunk

    const unsigned short* Abase = A + (size_t)bm * K;
    const unsigned short* Bbase = B + (size_t)bn * K;

// stage one K-half (16 KB) of matrix G into region (KH&3): 2 loads/thread.
// dest linear in tid (gload_lds requirement); source chunk pre-swizzled.
#define STAGE_H(G, DS, KH)                                                   \
    {                                                                        \
        _Pragma("unroll")                                                    \
        for (int s = 0; s < 2; ++s) {                                        \
            int cid = s * 512 + tid;                                         \
            int row = cid >> 2, c = cid & 3;                                 \
            int gch = c ^ (row & 3);                                         \
            gload_lds16((G) + (size_t)row * K + (KH) * 32 + gch * 8,         \
                        (DS) + ((KH) & 3) * 8192 + cid * 8);                 \
        }                                                                    \
    }

#define LDA(MH, KH)                                                          \
    _Pragma("unroll")                                                        \
    for (int m = 0; m < 4; ++m) {                                            \
        int row = wm * 128 + (MH) * 64 + m * 16 + frow;                      \
        af[m] = *(const bf16x8*)(Asw + ((KH) & 3) * 8192 + row * 32 +        \
                                 achunk * 8);                                \
    }

#define LDB(KH)                                                              \
    _Pragma("unroll")                                                        \
    for (int n = 0; n < 4; ++n) {                                            \
        int row = wn * 64 + n * 16 + frow;                                   \
        bfv[n] = *(const bf16x8*)(Bsw + ((KH) & 3) * 8192 + row * 32 +       \
                                  achunk * 8);                               \
    }

#define BARRIER                                                              \
    asm volatile("s_barrier" ::: "memory");                                  \
    __builtin_amdgcn_sched_barrier(0);

#define MFMA_PH(MH)                                                          \
    asm volatile("s_waitcnt lgkmcnt(0)" ::: "memory");                       \
    __builtin_amdgcn_sched_barrier(0);                                       \
    __builtin_amdgcn_s_setprio(1);                                           \
    _Pragma("unroll")                                                        \
    for (int m = 0; m < 4; ++m)                                              \
        _Pragma("unroll")                                                    \
        for (int n = 0; n < 4; ++n)                                          \
            acc[(MH) * 4 + m][n] = __builtin_amdgcn_mfma_f32_16x16x32_bf16(  \
                af[m], bfv[n], acc[(MH) * 4 + m][n], 0, 0, 0);               \
    __builtin_amdgcn_s_setprio(0);

    const int NKH = K >> 5;                  // K-halves (>= 4 for all calls)

    // prologue: stage khalves 0,1,2 (12 loads); ensure kh0 (oldest 4) done.
    STAGE_H(Abase, Asw, 0)
    STAGE_H(Bbase, Bsw, 0)
    STAGE_H(Abase, Asw, 1)
    STAGE_H(Bbase, Bsw, 1)
    STAGE_H(Abase, Asw, 2)
    STAGE_H(Bbase, Bsw, 2)
    asm volatile("s_waitcnt vmcnt(8)" ::: "memory");
    BARRIER

    for (int kh = 0; kh < NKH; ++kh) {
        bf16x8 af[4], bfv[4];
        // ---- phase A: frags(mh=0) + B-frags; stage A-half of kh+3 ----
        LDA(0, kh)
        LDB(kh)
        if (kh + 3 < NKH) { STAGE_H(Abase, Asw, kh + 3) }
        BARRIER
        MFMA_PH(0)
        BARRIER
        // ---- phase B: frags(mh=1) (B resident); stage B-half of kh+3 ----
        LDA(1, kh)
        if (kh + 3 < NKH) { STAGE_H(Bbase, Bsw, kh + 3) }
        {   // vmcnt ledger: ensure khalf kh+1 fully staged before its reads;
            // leave younger khalves in flight (never drain mid-loop).
            int rem = NKH - 1 - kh;
            if (rem >= 3) {
                asm volatile("s_waitcnt vmcnt(8)" ::: "memory");
            } else if (rem == 2) {
                asm volatile("s_waitcnt vmcnt(4)" ::: "memory");
            } else if (rem == 1) {
                asm volatile("s_waitcnt vmcnt(0)" ::: "memory");
            }
        }
        BARRIER
        MFMA_PH(1)
        BARRIER
    }
#undef STAGE_H
#undef LDA
#undef LDB
#undef BARRIER
#undef MFMA_PH

    const int r0 = (lane >> 4) * 4;
    const int cc = lane & 15;
    #pragma unroll
    for (int m = 0; m < 8; ++m) {
        #pragma unroll
        for (int n = 0; n < 4; ++n) {
            const int col = bn + wn * 64 + n * 16 + cc;
            #pragma unroll
            for (int j = 0; j < 4; ++j) {
                const int row = bm + wm * 128 + m * 16 + r0 + j;
                const size_t idx = (size_t)row * N + col;
                const float v = acc[m][n][j];
                if constexpr (EPI == 0) {
                    C[idx] = v;
                } else if constexpr (EPI == 1) {
                    float pre = v + bias[col];
                    float gt = 1.f / (1.f + expf(-pre));
                    C[idx] = p1[idx] + gt * bf2f(p2[idx]);
                } else if constexpr (EPI == 2) {
                    float pre = v + bias[col];
                    C[idx] = (OT)__float2bfloat16(pre / (1.f + expf(-pre)));
                } else if constexpr (EPI == 3) {
                    C[idx] = p1[idx] + v + bias[col];
                } else {
                    C[idx] = (OT)__float2bfloat16(v);
                }
            }
        }
    }
}

// ---------------------------------------------------------------------------
extern "C" void kernel_launch(void* const* d_in, const int* in_sizes, int n_in,
                              void* d_out, int out_size, void* d_ws, size_t ws_size,
                              hipStream_t stream)
{
    const float* x        = (const float*)d_in[0];
    const float* in_proj  = (const float*)d_in[1];
    const float* conv_w   = (const float*)d_in[2];
    const float* conv_b   = (const float*)d_in[3];
    const float* log_dec  = (const float*)d_in[4];
    const float* freq     = (const float*)d_in[5];
    const float* coup     = (const float*)d_in[6];
    const float* out_proj = (const float*)d_in[7];
    const float* gate_w   = (const float*)d_in[8];
    const float* gate_b   = (const float*)d_in[9];
    const float* mlp_w1   = (const float*)d_in[10];
    const float* mlp_b1   = (const float*)d_in[11];
    const float* mlp_w2   = (const float*)d_in[12];
    const float* mlp_b2   = (const float*)d_in[13];
    const float* ln1_g    = (const float*)d_in[14];
    const float* ln1_b    = (const float*)d_in[15];
    const float* ln2_g    = (const float*)d_in[16];
    const float* ln2_b    = (const float*)d_in[17];

    const int B = 4, T = 4096, D = 1024;
    const int M = B * T;                        // 16384

    float* out = (float*)d_out;                 // (M, D) final output 0
    float* eig = out + (size_t)M * D;           // (M, 128) final output 1
    float* bpre = eig;                          // temp: beta_pre in eig region

    char* w = (char*)d_ws;
    unsigned short* xn_bf = (unsigned short*)w; w += (size_t)M * 1024 * 2;
    float* x1             = (float*)w;          w += (size_t)M * 1024 * 4;
    float* beta           = (float*)w;          w += (size_t)M * 128 * 4;
    unsigned short* mid   = (unsigned short*)w; w += (size_t)M * 4096 * 2;
    unsigned short* eig_bf= (unsigned short*)w; w += (size_t)M * 128 * 2;
    unsigned short* wb_inproj = (unsigned short*)w; w += (size_t)128 * 1024 * 2;
    unsigned short* wb_outproj= (unsigned short*)w; w += (size_t)1024 * 128 * 2;
    unsigned short* wb_gate   = (unsigned short*)w; w += (size_t)1024 * 1024 * 2;
    unsigned short* wb_mlp1   = (unsigned short*)w; w += (size_t)4096 * 1024 * 2;
    unsigned short* wb_mlp2   = (unsigned short*)w; w += (size_t)1024 * 4096 * 2;
    // h (bf16) lives in the first 32 MB of mid: dead once mlp1 writes mid.
    unsigned short* h_bf = mid;

    // 0. weight conversions fp32 -> bf16
    cvt_bf16_kernel<<<(128 * 1024) / 2048, 256, 0, stream>>>(in_proj, wb_inproj, 128 * 1024);
    cvt_bf16_kernel<<<(1024 * 128) / 2048, 256, 0, stream>>>(out_proj, wb_outproj, 1024 * 128);
    cvt_bf16_kernel<<<(1024 * 1024) / 2048, 256, 0, stream>>>(gate_w, wb_gate, 1024 * 1024);
    cvt_bf16_kernel<<<(4096 * 1024) / 2048, 256, 0, stream>>>(mlp_w1, wb_mlp1, 4096 * 1024);
    cvt_bf16_kernel<<<(1024 * 4096) / 2048, 256, 0, stream>>>(mlp_w2, wb_mlp2, 1024 * 4096);

    // 1. LN1 -> bf16
    ln_kernel<<<M, 256, 0, stream>>>(x, ln1_g, ln1_b, xn_bf);
    // 2. in_proj: beta_pre = xn @ in_proj_w.T   (M,128) fp32
    gemm_mfma_f32out<<<dim3(1, M / 128), 256, 0, stream>>>(
        xn_bf, wb_inproj, bpre, M, 128, 1024);
    // 3. depthwise conv + silu
    conv_silu_kernel<<<(M * 128) / 256, 256, 0, stream>>>(bpre, conv_w, conv_b, beta, T);
    // 4. FIR + coupling -> eig (output 1, fp32) + eig_bf
    fir_coupling_kernel<<<B * (T / 64), 256, 0, stream>>>(
        beta, log_dec, freq, coup, eig, eig_bf, T);
    // 5. out_proj: h = eig @ out_proj_w.T   (M, D) bf16, staged in mid region
    gemm256<4, __hip_bfloat16><<<(M / 256) * (1024 / 256), 512, 0, stream>>>(
        eig_bf, wb_outproj, (__hip_bfloat16*)h_bf, M, 1024, 128,
        nullptr, nullptr, nullptr);
    // 6. gate fused: x1 = x + sigmoid(xn @ gate_w.T + gate_b) * h
    gemm256<1, float><<<(M / 256) * (1024 / 256), 512, 0, stream>>>(
        xn_bf, wb_gate, x1, M, 1024, 1024, gate_b, x, h_bf);
    // 7. LN2 -> bf16 (reuse xn_bf)
    ln_kernel<<<M, 256, 0, stream>>>(x1, ln2_g, ln2_b, xn_bf);
    // 8. mlp1: mid = bf16(silu(xn2 @ mlp_w1.T + b1))   (M, 4096)
    gemm256<2, __hip_bfloat16><<<(M / 256) * (4096 / 256), 512, 0, stream>>>(
        xn_bf, wb_mlp1, (__hip_bfloat16*)mid, M, 4096, 1024, mlp_b1, nullptr, nullptr);
    // 9. mlp2: out = x1 + mid @ mlp_w2.T + b2   (final output 0)
    gemm256<3, float><<<(M / 256) * (1024 / 256), 512, 0, stream>>>(
        mid, wb_mlp2, out, M, 1024, 4096, mlp_b2, x1, nullptr);
}